// Round 5
// baseline (171.898 us; speedup 1.0000x reference)
//
#include <hip/hip_runtime.h>
#include <float.h>

#define NB    16
#define CIN   64
#define NPT   16384
#define NRING 16
#define MAXR  1520
#define CNT   1024
#define LTOT  (NRING*MAXR)   // 24320
#define MBLK  380            // LTOT/64
#define NCH   128
#define NBLK1 (NB*CIN*2)     // 2048 blocks for K1 (b, cp, h)
#define IDXS  500            // ushort stride per ring

typedef float  fx4 __attribute__((ext_vector_type(4)));   // nontemporal-compatible

// K1: block = (b, cp, h). h selects 8 of the 16 conv groups (= input rings).
// LDS: xs = x[b][cp][h*8192 .. +8192] (32KB, per-ring rotate-by-4g swizzle),
//      ilds = ushort choice[b][g][1024:1520] for 8 groups (8KB). Total 40768B -> 4 blocks/CU.
// Inner loop is 100% LDS+VALU; identity positions (p<1024) need no index at all.
__global__ __launch_bounds__(512, 8) void k1_gather_conv(
    const float* __restrict__ x, const float* __restrict__ Wg,
    const float* __restrict__ bias, const float* __restrict__ gamma,
    const int* __restrict__ choice,
    float* __restrict__ p_sum, float* __restrict__ p_sqs,
    float* __restrict__ p_max, float* __restrict__ p_min)
{
    __shared__ float xs[8192];                 // 32 KB (reused as reduce scratch)
    __shared__ unsigned short ilds[8*IDXS];    // 8 KB

    const int blk = blockIdx.x;
    const int b  = blk >> 7;
    const int cp = (blk >> 1) & 63;
    const int h  = blk & 1;
    const int t  = threadIdx.x;

    // stage x half-row (nontemporal: single-use stream) with per-ring rotation
    {
        const fx4* src = (const fx4*)(x + ((size_t)(b*CIN + cp)) * NPT + h*8192);
        fx4* dst = (fx4*)xs;
        #pragma unroll
        for (int i = 0; i < 4; ++i) {
            const int J  = t + i*512;          // [0,2048) float4 units
            const int g8 = J >> 8;
            const int j  = J & 255;
            dst[(g8 << 8) + ((j + g8) & 255)] = __builtin_nontemporal_load(&src[J]);
        }
    }
    // stage random choice tail as ushort (values < 1024)
    {
        #pragma unroll
        for (int i = 0; i < 2; ++i) {
            const int J  = t + i*512;          // [0,1024)
            const int g8 = J >> 7;
            const int j  = J & 127;
            if (j < 124) {
                const int4 v = *(const int4*)(choice + ((size_t)(b*NRING + h*8 + g8))*MAXR + 1024 + j*4);
                ushort4 u;
                u.x = (unsigned short)v.x; u.y = (unsigned short)v.y;
                u.z = (unsigned short)v.z; u.w = (unsigned short)v.w;
                *(ushort4*)(ilds + g8*IDXS + j*4) = u;
            }
        }
    }
    __syncthreads();

    const int s  = t & 3;
    const int g8 = (t >> 2) & 7;
    const int r  = t >> 5;
    const int g  = h*8 + g8;

    float w[8][4], bs[8];
    bool needMin = false, needMax = false;
    #pragma unroll
    for (int o = 0; o < 8; ++o) {
        bs[o] = bias[g*8+o];
        const float gm = gamma[g*8+o];
        needMin |= (gm < 0.0f);
        needMax |= (gm >= 0.0f);
        #pragma unroll
        for (int c = 0; c < 4; ++c) w[o][c] = Wg[(g*8+o)*4 + c];
    }

    int mlo = (r*MAXR - cp + 63) >> 6;
    int mhi = ((r+1)*MAXR - cp + 63) >> 6;
    if (mhi > MBLK) mhi = MBLK;

    float smax[8], smin[8], ssum[8], ssq[8];
    #pragma unroll
    for (int o = 0; o < 8; ++o) { smax[o] = -FLT_MAX; smin[o] = FLT_MAX; ssum[o] = 0.f; ssq[o] = 0.f; }

    const int rot = g8 << 2;
    const float* __restrict__ xg = xs + (g8 << 10);
    const unsigned short* __restrict__ ig = ilds + g8*IDXS;

    if (!needMin) {
        for (int m = mlo + s; m < mhi; m += 4) {
            const int off2 = (m >= 264) ? (m - 264) : 0;
            const int lidx2 = ig[off2];
            const int idx2 = (m < 264) ? (760 + m) : lidx2;
            const int idx3 = ig[116 + m];
            const float v0 = xg[( m        + rot) & 1023];
            const float v1 = xg[((380 + m) + rot) & 1023];
            const float v2 = xg[( idx2     + rot) & 1023];
            const float v3 = xg[( idx3     + rot) & 1023];
            #pragma unroll
            for (int o = 0; o < 8; ++o) {
                float y = fmaf(w[o][0], v0, fmaf(w[o][1], v1,
                          fmaf(w[o][2], v2, fmaf(w[o][3], v3, bs[o]))));
                smax[o] = fmaxf(smax[o], y);
                ssum[o] += y;
                ssq[o]  = fmaf(y, y, ssq[o]);
            }
        }
    } else {
        for (int m = mlo + s; m < mhi; m += 4) {
            const int off2 = (m >= 264) ? (m - 264) : 0;
            const int lidx2 = ig[off2];
            const int idx2 = (m < 264) ? (760 + m) : lidx2;
            const int idx3 = ig[116 + m];
            const float v0 = xg[( m        + rot) & 1023];
            const float v1 = xg[((380 + m) + rot) & 1023];
            const float v2 = xg[( idx2     + rot) & 1023];
            const float v3 = xg[( idx3     + rot) & 1023];
            #pragma unroll
            for (int o = 0; o < 8; ++o) {
                float y = fmaf(w[o][0], v0, fmaf(w[o][1], v1,
                          fmaf(w[o][2], v2, fmaf(w[o][3], v3, bs[o]))));
                smax[o] = fmaxf(smax[o], y);
                smin[o] = fminf(smin[o], y);
                ssum[o] += y;
                ssq[o]  = fmaf(y, y, ssq[o]);
            }
        }
    }

    // combine the four s-copies (lanes xor 1, xor 2) — deterministic
    #pragma unroll
    for (int o = 0; o < 8; ++o) {
        smax[o] = fmaxf(smax[o], __shfl_xor(smax[o], 1));
        ssum[o] += __shfl_xor(ssum[o], 1);
        ssq[o]  += __shfl_xor(ssq[o], 1);
        smax[o] = fmaxf(smax[o], __shfl_xor(smax[o], 2));
        ssum[o] += __shfl_xor(ssum[o], 2);
        ssq[o]  += __shfl_xor(ssq[o], 2);
    }
    if (needMin) {
        #pragma unroll
        for (int o = 0; o < 8; ++o) {
            smin[o] = fminf(smin[o], __shfl_xor(smin[o], 1));
            smin[o] = fminf(smin[o], __shfl_xor(smin[o], 2));
        }
    }

    // ring partials, layout [b*64+cp][r][128ch]; this block owns ch = h*64 + g8*8 + o
    if (s == 0) {
        const size_t rowoff = (((size_t)(b*64 + cp))*NRING + r)*NCH + h*64 + g8*8;
        if (needMax) {
            float* base = p_max + rowoff;
            ((float4*)base)[0] = make_float4(smax[0], smax[1], smax[2], smax[3]);
            ((float4*)base)[1] = make_float4(smax[4], smax[5], smax[6], smax[7]);
        }
        if (needMin) {
            float* base = p_min + rowoff;
            ((float4*)base)[0] = make_float4(smin[0], smin[1], smin[2], smin[3]);
            ((float4*)base)[1] = make_float4(smin[4], smin[5], smin[6], smin[7]);
        }
    }

    // channel sum/sumsq block reduction over the 16 r's (reuse xs as scratch)
    __syncthreads();
    float* redS = xs;
    float* redQ = xs + 1100;
    if (s == 0) {
        #pragma unroll
        for (int o = 0; o < 8; ++o) {
            redS[(g8*8+o)*17 + r] = ssum[o];
            redQ[(g8*8+o)*17 + r] = ssq[o];
        }
    }
    __syncthreads();
    if (t < 64) {
        float S = 0.f, Q = 0.f;
        #pragma unroll
        for (int rr = 0; rr < 16; ++rr) {
            S += redS[t*17 + rr];
            Q += redQ[t*17 + rr];
        }
        p_sum[(size_t)blk*64 + t] = S;   // flat [2048][64], ch = h*64 + t
        p_sqs[(size_t)blk*64 + t] = Q;
    }
}

// K2a: per-channel mean / inv-std from the 2048x64 block partials (deterministic)
__global__ __launch_bounds__(256) void k2a_stats(
    const float* __restrict__ p_sum, const float* __restrict__ p_sqs,
    float2* __restrict__ stats)
{
    __shared__ float lsum[256], lsq[256];
    const int ch = blockIdx.x;
    const int hh = ch >> 6, c64 = ch & 63;
    float S = 0.f, Q = 0.f;
    for (int j = threadIdx.x; j < 1024; j += 256) {
        S += p_sum[(size_t)j*128 + hh*64 + c64];
        Q += p_sqs[(size_t)j*128 + hh*64 + c64];
    }
    lsum[threadIdx.x] = S; lsq[threadIdx.x] = Q;
    __syncthreads();
    for (int sred = 128; sred > 0; sred >>= 1) {
        if (threadIdx.x < sred) {
            lsum[threadIdx.x] += lsum[threadIdx.x + sred];
            lsq[threadIdx.x]  += lsq[threadIdx.x + sred];
        }
        __syncthreads();
    }
    if (threadIdx.x == 0) {
        const float inv = 1.0f / (float)((size_t)NB * LTOT);
        float mean = lsum[0] * inv;
        float var  = lsq[0] * inv - mean*mean;
        stats[ch] = make_float2(mean, rsqrtf(var + 1e-5f));
    }
}

// K23: fused pool-reduce + BN affine + broadcast write. block = (b, ch).
// Phase 1: reduce 64 cp x 16 r partials (L2-resident). Phase 2: write 64KB output row.
__global__ __launch_bounds__(256) void k23_pool_bcast(
    const float* __restrict__ p_max, const float* __restrict__ p_min,
    const float2* __restrict__ stats, const float* __restrict__ gamma,
    const float* __restrict__ beta, fx4* __restrict__ out)
{
    __shared__ float part[16][17];
    __shared__ float pool[16];
    const int bc = blockIdx.x;           // b*128 + ch
    const int b  = bc >> 7;
    const int ch = bc & 127;
    const int t  = threadIdx.x;
    const int r  = t >> 4;
    const int ck = t & 15;

    const float gm = gamma[ch];
    const bool useMax = (gm >= 0.0f);
    const float* __restrict__ src = useMax ? p_max : p_min;

    float v = useMax ? -FLT_MAX : FLT_MAX;
    #pragma unroll
    for (int k = 0; k < 4; ++k) {
        const int cpi = ck*4 + k;
        const float pv = src[(((size_t)(b*64 + cpi))*NRING + r)*NCH + ch];
        v = useMax ? fmaxf(v, pv) : fminf(v, pv);
    }
    part[r][ck] = v;
    __syncthreads();
    if (t < 16) {
        float acc = part[t][0];
        #pragma unroll
        for (int k = 1; k < 16; ++k)
            acc = useMax ? fmaxf(acc, part[t][k]) : fminf(acc, part[t][k]);
        const float2 st = stats[ch];
        pool[t] = gm * (acc - st.x) * st.y + beta[ch];
    }
    __syncthreads();

    fx4* __restrict__ dst = out + (size_t)bc * (NPT/4);
    #pragma unroll
    for (int i = 0; i < 16; ++i) {
        const int idx = t + i*256;            // [0,4096)
        const float vv = pool[idx >> 8];
        fx4 val; val.x = vv; val.y = vv; val.z = vv; val.w = vv;
        __builtin_nontemporal_store(val, &dst[idx]);
    }
}

extern "C" void kernel_launch(void* const* d_in, const int* in_sizes, int n_in,
                              void* d_out, int out_size, void* d_ws, size_t ws_size,
                              hipStream_t stream)
{
    const float* x     = (const float*)d_in[0];
    const float* Wg    = (const float*)d_in[1];
    const float* bias  = (const float*)d_in[2];
    const float* gamma = (const float*)d_in[3];
    const float* beta  = (const float*)d_in[4];
    const int* choice  = (const int*)d_in[6];

    float* p_sum = (float*)d_ws;                           // 2048*64
    float* p_sqs = p_sum + (size_t)2048*64;                // 2048*64
    float* p_max = p_sqs + (size_t)2048*64;                // 1024*16*128
    float* p_min = p_max + (size_t)1024*NRING*NCH;         // 1024*16*128
    float2* stats = (float2*)(p_min + (size_t)1024*NRING*NCH); // 128

    k1_gather_conv<<<NBLK1, 512, 0, stream>>>(x, Wg, bias, gamma, choice,
                                              p_sum, p_sqs, p_max, p_min);
    k2a_stats<<<NCH, 256, 0, stream>>>(p_sum, p_sqs, stats);
    k23_pool_bcast<<<NB*NCH, 256, 0, stream>>>(p_max, p_min, stats, gamma, beta, (fx4*)d_out);
}

// Round 6
// 64.578 us; speedup vs baseline: 2.6619x; 2.6619x over previous
//
#include <hip/hip_runtime.h>
#include <float.h>

#define NB    16
#define CIN   64
#define NPT   16384
#define NRING 16
#define MAXR  1520
#define CNT   1024
#define LTOT  (NRING*MAXR)   // 24320
#define MBLK  380            // LTOT/64
#define NCH   128
#define NBLK1 (NB*CIN*2)     // 2048 blocks for K1 (b, cp, h)
#define IDXS  500            // ushort stride per ring

typedef float fx4 __attribute__((ext_vector_type(4)));   // nontemporal-compatible

__device__ __forceinline__ float sload(float v) {
    // force a wave-uniform value into an SGPR
    return __int_as_float(__builtin_amdgcn_readfirstlane(__float_as_int(v)));
}

// K1: block = (b, cp, h). h selects 8 of the 16 conv groups (= input rings).
// Wave w (=t>>6) owns group g8=w (weights wave-uniform -> SGPR via readfirstlane).
// Lane: r = (lane>>2) output ring, s = lane&3 m-split.
// LDS: xs = 32KB x half-row (rotate-by-4g swizzle), ilds = 8KB ushort choice tails.
// Sign-fold: channels with gamma<0 use negated weights/bias; only max is tracked.
__global__ __launch_bounds__(512) void k1_gather_conv(
    const float* __restrict__ x, const float* __restrict__ Wg,
    const float* __restrict__ bias, const float* __restrict__ gamma,
    const int* __restrict__ choice,
    float* __restrict__ p_sum, float* __restrict__ p_sqs,
    float* __restrict__ p_max)
{
    __shared__ float xs[8192];                 // 32 KB (reused as reduce scratch)
    __shared__ unsigned short ilds[8*IDXS];    // 8 KB

    const int blk = blockIdx.x;
    const int b  = blk >> 7;
    const int cp = (blk >> 1) & 63;
    const int h  = blk & 1;
    const int t  = threadIdx.x;

    // stage x half-row (cached loads; x is L3-resident across replays) w/ per-ring rotation
    {
        const float4* src = (const float4*)(x + ((size_t)(b*CIN + cp)) * NPT + h*8192);
        float4* dst = (float4*)xs;
        #pragma unroll
        for (int i = 0; i < 4; ++i) {
            const int J  = t + i*512;          // [0,2048) float4 units
            const int gg = J >> 8;
            const int j  = J & 255;
            dst[(gg << 8) + ((j + gg) & 255)] = src[J];
        }
    }
    // stage random choice tail as ushort (values < 1024)
    {
        #pragma unroll
        for (int i = 0; i < 2; ++i) {
            const int J  = t + i*512;          // [0,1024)
            const int gg = J >> 7;
            const int j  = J & 127;
            if (j < 124) {
                const int4 v = *(const int4*)(choice + ((size_t)(b*NRING + h*8 + gg))*MAXR + 1024 + j*4);
                ushort4 u;
                u.x = (unsigned short)v.x; u.y = (unsigned short)v.y;
                u.z = (unsigned short)v.z; u.w = (unsigned short)v.w;
                *(ushort4*)(ilds + gg*IDXS + j*4) = u;
            }
        }
    }
    __syncthreads();

    const int g8   = t >> 6;          // wave-uniform
    const int lane = t & 63;
    const int r    = lane >> 2;
    const int s    = lane & 3;
    const int g    = h*8 + g8;

    // wave-uniform weights/bias, sign-folded, forced to SGPR
    float w[8][4], bs[8];
    #pragma unroll
    for (int o = 0; o < 8; ++o) {
        const int ch = g*8 + o;
        const float sg = (gamma[ch] < 0.0f) ? -1.0f : 1.0f;
        bs[o] = sload(sg * bias[ch]);
        #pragma unroll
        for (int c = 0; c < 4; ++c) w[o][c] = sload(sg * Wg[ch*4 + c]);
    }

    int mlo = (r*MAXR - cp + 63) >> 6;
    int mhi = ((r+1)*MAXR - cp + 63) >> 6;
    if (mhi > MBLK) mhi = MBLK;

    float smax[8], ssum[8], ssq[8];
    #pragma unroll
    for (int o = 0; o < 8; ++o) { smax[o] = -FLT_MAX; ssum[o] = 0.f; ssq[o] = 0.f; }

    const int rot = g8 << 2;
    const float* __restrict__ xg = xs + (g8 << 10);
    const unsigned short* __restrict__ ig = ilds + g8*IDXS;

    for (int m = mlo + s; m < mhi; m += 4) {
        // row c: p = c*380+m. c=0,1 identity; c=2 identity iff m<264; c=3 random.
        const int off2  = (m >= 264) ? (m - 264) : 0;
        const int lidx2 = ig[off2];
        const int idx2  = (m < 264) ? (760 + m) : lidx2;
        const int idx3  = ig[116 + m];
        const float v0 = xg[( m        + rot) & 1023];
        const float v1 = xg[((380 + m) + rot) & 1023];
        const float v2 = xg[( idx2     + rot) & 1023];
        const float v3 = xg[( idx3     + rot) & 1023];
        #pragma unroll
        for (int o = 0; o < 8; ++o) {
            float y = fmaf(w[o][0], v0, fmaf(w[o][1], v1,
                      fmaf(w[o][2], v2, fmaf(w[o][3], v3, bs[o]))));
            smax[o] = fmaxf(smax[o], y);
            ssum[o] += y;
            ssq[o]  = fmaf(y, y, ssq[o]);
        }
    }

    // combine the four s-copies (lanes xor 1, xor 2) — deterministic
    #pragma unroll
    for (int o = 0; o < 8; ++o) {
        smax[o] = fmaxf(smax[o], __shfl_xor(smax[o], 1));
        ssum[o] += __shfl_xor(ssum[o], 1);
        ssq[o]  += __shfl_xor(ssq[o], 1);
        smax[o] = fmaxf(smax[o], __shfl_xor(smax[o], 2));
        ssum[o] += __shfl_xor(ssum[o], 2);
        ssq[o]  += __shfl_xor(ssq[o], 2);
    }

    // ring partials, layout [b*64+cp][r][128ch]; this block owns ch = h*64 + g8*8 + o
    if (s == 0) {
        float* base = p_max + (((size_t)(b*64 + cp))*NRING + r)*NCH + h*64 + g8*8;
        ((float4*)base)[0] = make_float4(smax[0], smax[1], smax[2], smax[3]);
        ((float4*)base)[1] = make_float4(smax[4], smax[5], smax[6], smax[7]);
    }

    // channel sum/sumsq block reduction over the 16 r's (reuse xs as scratch)
    __syncthreads();
    float* redS = xs;
    float* redQ = xs + 1100;
    if (s == 0) {
        #pragma unroll
        for (int o = 0; o < 8; ++o) {
            redS[(g8*8+o)*17 + r] = ssum[o];
            redQ[(g8*8+o)*17 + r] = ssq[o];
        }
    }
    __syncthreads();
    if (t < 64) {
        float S = 0.f, Q = 0.f;
        #pragma unroll
        for (int rr = 0; rr < 16; ++rr) {
            S += redS[t*17 + rr];
            Q += redQ[t*17 + rr];
        }
        const float sg = (gamma[h*64 + t] < 0.0f) ? -1.0f : 1.0f;
        p_sum[(size_t)blk*64 + t] = sg * S;   // un-fold the sign for BN stats
        p_sqs[(size_t)blk*64 + t] = Q;        // sign-invariant
    }
}

// K2a: per-channel mean / inv-std from the 2048x64 block partials (deterministic)
__global__ __launch_bounds__(256) void k2a_stats(
    const float* __restrict__ p_sum, const float* __restrict__ p_sqs,
    float2* __restrict__ stats)
{
    __shared__ float lsum[256], lsq[256];
    const int ch = blockIdx.x;
    const int hh = ch >> 6, c64 = ch & 63;
    float S = 0.f, Q = 0.f;
    for (int j = threadIdx.x; j < 1024; j += 256) {
        S += p_sum[(size_t)j*128 + hh*64 + c64];
        Q += p_sqs[(size_t)j*128 + hh*64 + c64];
    }
    lsum[threadIdx.x] = S; lsq[threadIdx.x] = Q;
    __syncthreads();
    for (int sred = 128; sred > 0; sred >>= 1) {
        if (threadIdx.x < sred) {
            lsum[threadIdx.x] += lsum[threadIdx.x + sred];
            lsq[threadIdx.x]  += lsq[threadIdx.x + sred];
        }
        __syncthreads();
    }
    if (threadIdx.x == 0) {
        const float inv = 1.0f / (float)((size_t)NB * LTOT);
        float mean = lsum[0] * inv;
        float var  = lsq[0] * inv - mean*mean;
        stats[ch] = make_float2(mean, rsqrtf(var + 1e-5f));
    }
}

// K23: fused pool-reduce + BN affine + broadcast write. block = (b, ch).
// p_max holds sign-folded extremes; raw = (gamma>=0 ? acc : -acc).
__global__ __launch_bounds__(256) void k23_pool_bcast(
    const float* __restrict__ p_max, const float2* __restrict__ stats,
    const float* __restrict__ gamma, const float* __restrict__ beta,
    fx4* __restrict__ out)
{
    __shared__ float part[16][17];
    __shared__ float pool[16];
    const int bc = blockIdx.x;           // b*128 + ch
    const int b  = bc >> 7;
    const int ch = bc & 127;
    const int t  = threadIdx.x;
    const int r  = t >> 4;
    const int ck = t & 15;

    float v = -FLT_MAX;
    #pragma unroll
    for (int k = 0; k < 4; ++k) {
        const int cpi = ck*4 + k;
        v = fmaxf(v, p_max[(((size_t)(b*64 + cpi))*NRING + r)*NCH + ch]);
    }
    part[r][ck] = v;
    __syncthreads();
    if (t < 16) {
        float acc = part[t][0];
        #pragma unroll
        for (int k = 1; k < 16; ++k) acc = fmaxf(acc, part[t][k]);
        const float gm = gamma[ch];
        const float raw = (gm >= 0.0f) ? acc : -acc;
        const float2 st = stats[ch];
        pool[t] = gm * (raw - st.x) * st.y + beta[ch];
    }
    __syncthreads();

    fx4* __restrict__ dst = out + (size_t)bc * (NPT/4);
    #pragma unroll
    for (int i = 0; i < 16; ++i) {
        const int idx = t + i*256;            // [0,4096)
        const float vv = pool[idx >> 8];
        fx4 val; val.x = vv; val.y = vv; val.z = vv; val.w = vv;
        __builtin_nontemporal_store(val, &dst[idx]);
    }
}

extern "C" void kernel_launch(void* const* d_in, const int* in_sizes, int n_in,
                              void* d_out, int out_size, void* d_ws, size_t ws_size,
                              hipStream_t stream)
{
    const float* x     = (const float*)d_in[0];
    const float* Wg    = (const float*)d_in[1];
    const float* bias  = (const float*)d_in[2];
    const float* gamma = (const float*)d_in[3];
    const float* beta  = (const float*)d_in[4];
    const int* choice  = (const int*)d_in[6];

    float* p_sum = (float*)d_ws;                           // 2048*64
    float* p_sqs = p_sum + (size_t)2048*64;                // 2048*64
    float* p_max = p_sqs + (size_t)2048*64;                // 1024*16*128
    float2* stats = (float2*)(p_max + (size_t)1024*NRING*NCH); // 128

    k1_gather_conv<<<NBLK1, 512, 0, stream>>>(x, Wg, bias, gamma, choice,
                                              p_sum, p_sqs, p_max);
    k2a_stats<<<NCH, 256, 0, stream>>>(p_sum, p_sqs, stats);
    k23_pool_bcast<<<NB*NCH, 256, 0, stream>>>(p_max, stats, gamma, beta, (fx4*)d_out);
}

// Round 7
// 63.542 us; speedup vs baseline: 2.7052x; 1.0163x over previous
//
#include <hip/hip_runtime.h>
#include <float.h>

#define NB    16
#define CIN   64
#define NPT   16384
#define NRING 16
#define MAXR  1520
#define LTOT  (NRING*MAXR)   // 24320
#define MBLK  380            // LTOT/64
#define NCH   128
#define NBLK1 (NB*CIN*2)     // 2048 blocks for K1 (b, cp, h)
#define IDXS  500            // ushort stride per ring

typedef float fx4 __attribute__((ext_vector_type(4)));

__device__ __forceinline__ float sload(float v) {
    // force a wave-uniform value into an SGPR
    return __int_as_float(__builtin_amdgcn_readfirstlane(__float_as_int(v)));
}

// K1: block = (b, cp, h); h = which 8 of 16 conv groups. Wave w owns group g8=w
// (weights wave-uniform -> SGPR). Lane: r = lane>>2 (output ring), s = lane&3.
// Per-thread valid m-count is 5 or 6 (ring span 23/24 m's, 4-way s split):
// 5 unrolled iterations with preloaded indices + 1 guarded tail.
// Sign-fold: gamma<0 channels use negated weights/bias; only max tracked.
__global__ __launch_bounds__(512) void k1_gather_conv(
    const float* __restrict__ x, const float* __restrict__ Wg,
    const float* __restrict__ bias, const float* __restrict__ gamma,
    const int* __restrict__ choice,
    float* __restrict__ p_sum, float* __restrict__ p_sqs,
    float* __restrict__ p_max)
{
    __shared__ float xs[8192];                 // 32 KB (reused as reduce scratch)
    __shared__ unsigned short ilds[8*IDXS];    // 8 KB; total 40768B -> 4 blocks/CU

    const int blk = blockIdx.x;
    const int b  = blk >> 7;
    const int cp = (blk >> 1) & 63;
    const int h  = blk & 1;
    const int t  = threadIdx.x;

    // linear coalesced stage of the x half-row
    {
        const float4* src = (const float4*)(x + ((size_t)(b*CIN + cp)) * NPT + h*8192);
        float4* dst = (float4*)xs;
        #pragma unroll
        for (int i = 0; i < 4; ++i) dst[t + i*512] = src[t + i*512];
    }
    // stage random choice tails as ushort (values < 1024)
    {
        #pragma unroll
        for (int i = 0; i < 2; ++i) {
            const int J  = t + i*512;          // [0,1024)
            const int gg = J >> 7;
            const int j  = J & 127;
            if (j < 124) {
                const int4 v = *(const int4*)(choice + ((size_t)(b*NRING + h*8 + gg))*MAXR + 1024 + j*4);
                ushort4 u;
                u.x = (unsigned short)v.x; u.y = (unsigned short)v.y;
                u.z = (unsigned short)v.z; u.w = (unsigned short)v.w;
                *(ushort4*)(ilds + gg*IDXS + j*4) = u;
            }
        }
    }
    __syncthreads();

    const int g8   = t >> 6;          // wave-uniform
    const int lane = t & 63;
    const int r    = lane >> 2;
    const int s    = lane & 3;
    const int g    = h*8 + g8;

    float w[8][4], bs[8];
    #pragma unroll
    for (int o = 0; o < 8; ++o) {
        const int ch = g*8 + o;
        const float sg = (gamma[ch] < 0.0f) ? -1.0f : 1.0f;
        bs[o] = sload(sg * bias[ch]);
        #pragma unroll
        for (int c = 0; c < 4; ++c) w[o][c] = sload(sg * Wg[ch*4 + c]);
    }

    const int mlo = (r*MAXR - cp + 63) >> 6;
    int mhi = ((r+1)*MAXR - cp + 63) >> 6;
    if (mhi > MBLK) mhi = MBLK;

    const float* __restrict__ xg = xs + (g8 << 10);
    const unsigned short* __restrict__ ig = ilds + g8*IDXS;

    float smax[8], ssum[8], ssq[8];
    #pragma unroll
    for (int o = 0; o < 8; ++o) { smax[o] = -FLT_MAX; ssum[o] = 0.f; ssq[o] = 0.f; }

    const int m0 = mlo + s;

    // preload all indices for the 5 guaranteed iterations (independent u16 loads)
    int ix2[5], ix3[5];
    #pragma unroll
    for (int k = 0; k < 5; ++k) {
        const int m = m0 + 4*k;
        const int off2 = (m >= 264) ? (m - 264) : 0;
        const int l2 = ig[off2];
        ix2[k] = (m < 264) ? (760 + m) : l2;
        ix3[k] = ig[116 + m];
    }
    #pragma unroll
    for (int k = 0; k < 5; ++k) {
        const int m = m0 + 4*k;
        const float v0 = xg[m];           // c=0: identity
        const float v1 = xg[380 + m];     // c=1: identity
        const float v2 = xg[ix2[k]];      // c=2: identity if m<264 else random
        const float v3 = xg[ix3[k]];      // c=3: random
        #pragma unroll
        for (int o = 0; o < 8; ++o) {
            float y = fmaf(w[o][0], v0, fmaf(w[o][1], v1,
                      fmaf(w[o][2], v2, fmaf(w[o][3], v3, bs[o]))));
            smax[o] = fmaxf(smax[o], y);
            ssum[o] += y;
            ssq[o]  = fmaf(y, y, ssq[o]);
        }
    }
    {   // guarded 6th iteration
        const int m = m0 + 20;
        if (m < mhi) {
            const int off2 = (m >= 264) ? (m - 264) : 0;
            const int l2 = ig[off2];
            const int idx2 = (m < 264) ? (760 + m) : l2;
            const int idx3 = ig[116 + m];
            const float v0 = xg[m];
            const float v1 = xg[380 + m];
            const float v2 = xg[idx2];
            const float v3 = xg[idx3];
            #pragma unroll
            for (int o = 0; o < 8; ++o) {
                float y = fmaf(w[o][0], v0, fmaf(w[o][1], v1,
                          fmaf(w[o][2], v2, fmaf(w[o][3], v3, bs[o]))));
                smax[o] = fmaxf(smax[o], y);
                ssum[o] += y;
                ssq[o]  = fmaf(y, y, ssq[o]);
            }
        }
    }

    // combine the four s-copies (lanes xor 1, xor 2) — deterministic
    #pragma unroll
    for (int o = 0; o < 8; ++o) {
        smax[o] = fmaxf(smax[o], __shfl_xor(smax[o], 1));
        ssum[o] += __shfl_xor(ssum[o], 1);
        ssq[o]  += __shfl_xor(ssq[o], 1);
        smax[o] = fmaxf(smax[o], __shfl_xor(smax[o], 2));
        ssum[o] += __shfl_xor(ssum[o], 2);
        ssq[o]  += __shfl_xor(ssq[o], 2);
    }

    // ring partials, layout [b*64+cp][r][128ch]; this block owns ch = h*64 + g8*8 + o
    if (s == 0) {
        float* base = p_max + (((size_t)(b*64 + cp))*NRING + r)*NCH + h*64 + g8*8;
        ((float4*)base)[0] = make_float4(smax[0], smax[1], smax[2], smax[3]);
        ((float4*)base)[1] = make_float4(smax[4], smax[5], smax[6], smax[7]);
    }

    // channel sum/sumsq block reduction over the 16 r's (reuse xs as scratch)
    __syncthreads();
    float* redS = xs;
    float* redQ = xs + 1100;
    if (s == 0) {
        #pragma unroll
        for (int o = 0; o < 8; ++o) {
            redS[(g8*8+o)*17 + r] = ssum[o];
            redQ[(g8*8+o)*17 + r] = ssq[o];
        }
    }
    __syncthreads();
    if (t < 64) {
        float S = 0.f, Q = 0.f;
        #pragma unroll
        for (int rr = 0; rr < 16; ++rr) {
            S += redS[t*17 + rr];
            Q += redQ[t*17 + rr];
        }
        const float sg = (gamma[h*64 + t] < 0.0f) ? -1.0f : 1.0f;
        p_sum[(size_t)blk*64 + t] = sg * S;   // un-fold the sign for BN stats
        p_sqs[(size_t)blk*64 + t] = Q;        // sign-invariant
    }
}

// K23: fused {channel stats + pool-reduce + BN affine + broadcast write}.
// block = (b, ch). Stats are recomputed redundantly per block (8KB L2 reads).
__global__ __launch_bounds__(256) void k23_pool_bcast(
    const float* __restrict__ p_sum, const float* __restrict__ p_sqs,
    const float* __restrict__ p_max,
    const float* __restrict__ gamma, const float* __restrict__ beta,
    fx4* __restrict__ out)
{
    __shared__ float part[16][17];
    __shared__ float wsum[4], wsq[4];
    __shared__ float pool[16];
    const int bc = blockIdx.x;           // b*128 + ch
    const int b  = bc >> 7;
    const int ch = bc & 127;
    const int t  = threadIdx.x;
    const int hh = ch >> 6, c64 = ch & 63;

    // p_max slice reduce (sign-folded maxima)
    const int r = t >> 4, ck = t & 15;
    float v = -FLT_MAX;
    #pragma unroll
    for (int k = 0; k < 4; ++k) {
        const int cpi = ck*4 + k;
        v = fmaxf(v, p_max[(((size_t)(b*64 + cpi))*NRING + r)*NCH + ch]);
    }

    // channel stats: sum 1024 (b,cp) partials for this ch
    float S = 0.f, Q = 0.f;
    #pragma unroll
    for (int i = 0; i < 4; ++i) {
        const int jj = t + i*256;        // [0,1024)
        const int b2 = jj >> 6, cp2 = jj & 63;
        const int kb = b2*128 + cp2*2 + hh;
        S += p_sum[(size_t)kb*64 + c64];
        Q += p_sqs[(size_t)kb*64 + c64];
    }
    #pragma unroll
    for (int off = 1; off < 64; off <<= 1) {
        S += __shfl_xor(S, off);
        Q += __shfl_xor(Q, off);
    }
    part[r][ck] = v;
    if ((t & 63) == 0) { wsum[t >> 6] = S; wsq[t >> 6] = Q; }
    __syncthreads();

    if (t < 16) {
        const float inv = 1.0f / (float)((size_t)NB * LTOT);
        const float Sa = wsum[0] + wsum[1] + wsum[2] + wsum[3];
        const float Qa = wsq[0] + wsq[1] + wsq[2] + wsq[3];
        const float mean = Sa * inv;
        const float var  = Qa * inv - mean*mean;
        const float istd = rsqrtf(var + 1e-5f);
        float acc = part[t][0];
        #pragma unroll
        for (int k = 1; k < 16; ++k) acc = fmaxf(acc, part[t][k]);
        const float gm = gamma[ch];
        const float raw = (gm >= 0.0f) ? acc : -acc;   // un-fold sign
        pool[t] = gm * (raw - mean) * istd + beta[ch];
    }
    __syncthreads();

    fx4* __restrict__ dst = out + (size_t)bc * (NPT/4);
    #pragma unroll
    for (int i = 0; i < 16; ++i) {
        const int idx = t + i*256;            // [0,4096)
        const float vv = pool[idx >> 8];
        fx4 val; val.x = vv; val.y = vv; val.z = vv; val.w = vv;
        __builtin_nontemporal_store(val, &dst[idx]);
    }
}

extern "C" void kernel_launch(void* const* d_in, const int* in_sizes, int n_in,
                              void* d_out, int out_size, void* d_ws, size_t ws_size,
                              hipStream_t stream)
{
    const float* x     = (const float*)d_in[0];
    const float* Wg    = (const float*)d_in[1];
    const float* bias  = (const float*)d_in[2];
    const float* gamma = (const float*)d_in[3];
    const float* beta  = (const float*)d_in[4];
    const int* choice  = (const int*)d_in[6];

    float* p_sum = (float*)d_ws;                           // 2048*64
    float* p_sqs = p_sum + (size_t)2048*64;                // 2048*64
    float* p_max = p_sqs + (size_t)2048*64;                // 1024*16*128

    k1_gather_conv<<<NBLK1, 512, 0, stream>>>(x, Wg, bias, gamma, choice,
                                              p_sum, p_sqs, p_max);
    k23_pool_bcast<<<NB*NCH, 256, 0, stream>>>(p_sum, p_sqs, p_max,
                                               gamma, beta, (fx4*)d_out);
}